// Round 8
// baseline (1411.800 us; speedup 1.0000x reference)
//
#include <hip/hip_runtime.h>
#include <hip/hip_bf16.h>

// ---------------- problem constants ----------------
#define HID 128
static const int N_NODES = 50000;
static const int N_EDGES = 20000;
static const int M_COPIES = 400000;
static const int L_EDGES = 800000;
static const int NBATCH = 32;
static const int NCLS = 10;
#define INV_STD 0.9999950000374997f   // 1/sqrt(1+1e-5)
#define IDX_CAP 384                   // per-chunk item cap (block avg 128)
#define PKSHIFT 19                    // packed entry: (rloc<<19)|val, val<2^19
#define PKMASK  0x7FFFF

typedef __attribute__((ext_vector_type(4))) float f32x4;
typedef __attribute__((ext_vector_type(8))) short short8;      // 8 bf16 lanes
typedef __attribute__((ext_vector_type(8))) unsigned short ushort8;
typedef __attribute__((ext_vector_type(4))) unsigned short u16x4;  // 'ushort4' collides with HIP header

__device__ __forceinline__ float bf2f(unsigned short u) {
    union { unsigned u; float f; } v; v.u = ((unsigned)u) << 16; return v.f;
}
__device__ __forceinline__ unsigned short f2bf(float f) {
    union { float f; unsigned u; } v; v.f = f;
    unsigned r = v.u + 0x7FFFu + ((v.u >> 16) & 1u);   // RNE
    return (unsigned short)(r >> 16);
}
__device__ __forceinline__ void gatomic_add(float* p, float v) {
    unsafeAtomicAdd(p, v);
}

// Swizzled Xs addressing: logical [chunk c][row r][8 bf16], 16 B per (c,r).
// byte = (c*1024 + r*16) ^ ((c&7)<<4) -> gather writes (c fast-varying across
// lanes) land on 8 distinct 16B slots instead of 1 (proven: conflicts 2.88e7->8e5).
__device__ __forceinline__ unsigned short* xs_addr(unsigned short* Xs, int c, int r) {
    int byte = ((c * 64 + r) * 16) ^ ((c & 7) << 4);
    return (unsigned short*)((char*)Xs + byte);
}

// Async DMA of one wave's 1KB quarter of a 4KB W-eighth into LDS (linear copy
// from the eighth-linear Wt image: conflict-free writes, no VGPR round trip).
__device__ __forceinline__ void stage8(const unsigned short* __restrict__ Wmat, int e,
                                       unsigned short* buf, int wave, int lane) {
    const char* g = (const char*)Wmat + ((size_t)e << 12) + (wave << 10) + (lane << 4);
    char* l = (char*)buf + (wave << 10);
    __builtin_amdgcn_global_load_lds(
        (const __attribute__((address_space(1))) unsigned int*)g,
        (__attribute__((address_space(3))) unsigned int*)l,
        16, 0, 0);
}

// Counted-vmcnt barrier (T4): keep DMAs in flight ACROSS the barrier.
// vmem ledger in the GEMM loops is exact: only stage8 DMAs are outstanding
// (gather-phase loads are drained by the gather-end __syncthreads).
template<int N>
__device__ __forceinline__ void pipe_barrier() {
    if constexpr (N == 0) asm volatile("s_waitcnt vmcnt(0)" ::: "memory");
    else                  asm volatile("s_waitcnt vmcnt(1)" ::: "memory");
    __builtin_amdgcn_s_barrier();
    asm volatile("" ::: "memory");
}

// 4 chained MFMAs: one eighth (16 out-channels) x full K for this wave's rows.
__device__ __forceinline__ void mfma4(const unsigned short* Ws, const short8* xv,
                                      f32x4& a, int quad, int ln) {
#pragma unroll
    for (int kc = 0; kc < 4; ++kc) {
        short8 wa = *(const short8*)(Ws + (((kc * 4 + quad) * 16) + ln) * 8);
        a = __builtin_amdgcn_mfma_f32_16x16x32_bf16(wa, xv[kc], a, 0, 0, 0);
    }
}

// ---------------- weight prep: eighth-linear layout ----------------
__global__ __launch_bounds__(256) void prep_w(const float* __restrict__ We,
                                              const float* __restrict__ Wg,
                                              unsigned short* __restrict__ Wt) {
    int t = blockIdx.x * 256 + threadIdx.x;       // 17*16384
    if (t >= 17 * 16384) return;
    int mat = t >> 14, rem = t & 16383;
    int h = rem >> 11, r2 = rem & 2047;
    int gg = r2 >> 7, r3 = r2 & 127;
    int n = r3 >> 3, j = r3 & 7;
    int k = gg * 8 + j, col = h * 16 + n;
    const float* src = (mat == 0) ? We : (Wg + (size_t)(mat - 1) * 16384);
    Wt[t] = f2bf(src[k * 128 + col]);
}

// ---------------- CSR build ----------------
__global__ __launch_bounds__(256) void hist2_k(
    const int* __restrict__ iA, int nA, int* __restrict__ cA,
    const int* __restrict__ iB, int nB, int* __restrict__ cB, int shift) {
    int t = blockIdx.x * 256 + threadIdx.x;
    if (t < nA) atomicAdd(&cA[iA[t] >> shift], 1);
    if (t < nB) atomicAdd(&cB[iB[t] >> shift], 1);
}

__global__ __launch_bounds__(256) void scan1d_k(
    int* __restrict__ a0, int n0, int* __restrict__ p0,
    int* __restrict__ a1, int n1, int* __restrict__ p1) {
    int* a    = blockIdx.y ? a1 : a0;
    int n     = blockIdx.y ? n1 : n0;
    int* part = blockIdx.y ? p1 : p0;
    if ((int)(blockIdx.x * 256) >= n) return;   // uniform per block
    __shared__ int s[256];
    int i = blockIdx.x * 256 + threadIdx.x;
    int v = (i < n) ? a[i] : 0;
    s[threadIdx.x] = v;
    __syncthreads();
#pragma unroll
    for (int d = 1; d < 256; d <<= 1) {
        int t = (threadIdx.x >= d) ? s[threadIdx.x - d] : 0;
        __syncthreads();
        s[threadIdx.x] += t;
        __syncthreads();
    }
    if (i < n) a[i] = s[threadIdx.x] - v;
    if (threadIdx.x == 255) part[blockIdx.x] = s[255];
}

__global__ __launch_bounds__(256) void scan2d_k(
    int* __restrict__ p0, int nb0, int* __restrict__ p1, int nb1) {
    int* part = blockIdx.x ? p1 : p0;
    int nb    = blockIdx.x ? nb1 : nb0;
    __shared__ int s[256];
    __shared__ int carry;
    if (threadIdx.x == 0) carry = 0;
    __syncthreads();
    for (int base = 0; base < nb; base += 256) {
        int i = base + threadIdx.x;
        int v = (i < nb) ? part[i] : 0;
        s[threadIdx.x] = v;
        __syncthreads();
#pragma unroll
        for (int d = 1; d < 256; d <<= 1) {
            int t = (threadIdx.x >= d) ? s[threadIdx.x - d] : 0;
            __syncthreads();
            s[threadIdx.x] += t;
            __syncthreads();
        }
        if (i < nb) part[i] = carry + s[threadIdx.x] - v;
        __syncthreads();
        if (threadIdx.x == 0) carry += s[255];
        __syncthreads();
    }
}

__global__ __launch_bounds__(256) void scan3d_k(
    int* __restrict__ a0, int n0, const int* __restrict__ p0,
    int* __restrict__ a1, int n1, const int* __restrict__ p1) {
    int* a          = blockIdx.y ? a1 : a0;
    int n           = blockIdx.y ? n1 : n0;
    const int* part = blockIdx.y ? p1 : p0;
    int i = blockIdx.x * 256 + threadIdx.x;
    if (i < n) a[i] += part[blockIdx.x];
}

// Block-granular edge fill: region key = dst>>6 (6250 regions of 64 rows).
// ONE packed int2 store per edge: {.x=(rloc<<19)|src, .y=(rloc<<19)|remap[src]}.
__global__ __launch_bounds__(256) void fill_edgeblk2_k(
    const int* __restrict__ sA, const int* __restrict__ dA, const int* __restrict__ rA,
    int nA, int* __restrict__ oA, int2* __restrict__ pkA,
    const int* __restrict__ sB, const int* __restrict__ dB, const int* __restrict__ rB,
    int nB, int* __restrict__ oB, int2* __restrict__ pkB) {
    int t = blockIdx.x * 256 + threadIdx.x;
    if (t < nA) {
        int d = dA[t]; int pos = atomicAdd(&oA[d >> 6], 1);
        int s = sA[t]; int rl = (d & 63) << PKSHIFT;
        pkA[pos] = (int2){rl | s, rl | rA[s]};
    }
    if (t < nB) {
        int d = dB[t]; int pos = atomicAdd(&oB[d >> 6], 1);
        int s = sB[t]; int rl = (d & 63) << PKSHIFT;
        pkB[pos] = (int2){rl | s, rl | rB[s]};
    }
}

// Pool fill, rank form: rk[m] = position of copy m in segment-sorted order.
// Sequential rk writes (coalesced) instead of the old random items[pos]=m.
__global__ __launch_bounds__(256) void fill_pool2_k(
    const int* __restrict__ gA, int nA, int* __restrict__ oA, int* __restrict__ rkA,
    const int* __restrict__ gB, int nB, int* __restrict__ oB, int* __restrict__ rkB) {
    int t = blockIdx.x * 256 + threadIdx.x;
    if (t < nA) rkA[t] = atomicAdd(&oA[gA[t]], 1);
    if (t < nB) rkB[t] = atomicAdd(&oB[gB[t]], 1);
}

// ---------------- pool segment sum: wave-per-segment, STREAMING ----------------
// Xb2 is written pool-sorted (conv<false> stores row m at rank[m]), so each
// segment's rows are contiguous: pure streaming reads, no index indirection.
// PROJ=true additionally computes y[seg] += relu(pooled) @ Wp (folds proj_y).
template<bool PROJ>
__global__ __launch_bounds__(256) void segsum_pool(
    const unsigned short* __restrict__ tbl, const int* __restrict__ off,
    unsigned short* __restrict__ out, int nseg,
    const float* __restrict__ Wp, float* __restrict__ y)
{
    int wave = threadIdx.x >> 6, lane = threadIdx.x & 63;
    int seg = blockIdx.x * 4 + wave;
    if (seg >= nseg) return;
    int start = (seg == 0) ? 0 : off[seg - 1];
    int end = off[seg];
    int g = lane & 15, sub = lane >> 4;
    float a[8] = {0.f, 0.f, 0.f, 0.f, 0.f, 0.f, 0.f, 0.f};
    int p = start + sub;
    for (; p + 4 < end; p += 8) {
        ushort8 v0 = *(const ushort8*)(tbl + (size_t)p * 128 + g * 8);
        ushort8 v1 = *(const ushort8*)(tbl + (size_t)(p + 4) * 128 + g * 8);
#pragma unroll
        for (int j = 0; j < 8; ++j) a[j] += bf2f(v0[j]) + bf2f(v1[j]);
    }
    if (p < end) {
        ushort8 v = *(const ushort8*)(tbl + (size_t)p * 128 + g * 8);
#pragma unroll
        for (int j = 0; j < 8; ++j) a[j] += bf2f(v[j]);
    }
#pragma unroll
    for (int j = 0; j < 8; ++j) {
        a[j] += __shfl_xor(a[j], 16, 64);
        a[j] += __shfl_xor(a[j], 32, 64);
    }
    if (sub == 0) {
        float r[8];
        ushort8 ov;
#pragma unroll
        for (int j = 0; j < 8; ++j) { r[j] = fmaxf(a[j], 0.f); ov[j] = f2bf(r[j]); }
        *(ushort8*)(out + (size_t)seg * 128 + g * 8) = ov;
        if (PROJ) {
            float part[NCLS];
#pragma unroll
            for (int c = 0; c < NCLS; ++c) part[c] = 0.f;
#pragma unroll
            for (int j = 0; j < 8; ++j) {
                float xv = r[j];
                const float* w = Wp + (g * 8 + j) * NCLS;
#pragma unroll
                for (int c = 0; c < NCLS; ++c) part[c] += xv * w[c];
            }
            // reduce over the 16 g-lanes (all partners within lanes 0..15: active)
#pragma unroll
            for (int d = 1; d < 16; d <<= 1)
#pragma unroll
                for (int c = 0; c < NCLS; ++c) part[c] += __shfl_xor(part[c], d, 64);
            if (g == 0) {
                float* yp = y + (size_t)seg * NCLS;
#pragma unroll
                for (int c = 0; c < NCLS; ++c) yp[c] += part[c];
            }
        }
    }
}

// ---------------- fused GIN conv: 256 thr / 64 rows ----------------
// gather-segsum + linear1+ReLU + linear2+BN(+ReLU).
// R5-proven config: 5 blocks/CU, Wsb[3] counted-vmcnt pipeline, 1-wide
// 4-row-interleaved ballot gather (2-wide regressed, R7; 6 blocks/CU
// spilled via the 42-VGPR launch_bounds cap, R6).
// CONV0=false writes its output row m at outIdx[m] (pool rank) so the
// following segsum streams contiguously.
template<bool CONV0>
__global__ __launch_bounds__(256, 5) void fused_conv(
    const unsigned short* __restrict__ tbl,
    const int* __restrict__ self_idx,
    const int* __restrict__ blkOff, const int2* __restrict__ edgePk,
    const int* __restrict__ outIdx,
    const float* __restrict__ eps_ptr,
    const unsigned short* __restrict__ W1t, const float* __restrict__ b1,
    const unsigned short* __restrict__ W2t, const float* __restrict__ b2,
    const float* __restrict__ gam, const float* __restrict__ bet,
    unsigned short* __restrict__ out)
{
    __shared__ __align__(16) unsigned short Xs[16 * 64 * 8];  // 16 KB, swizzled
    __shared__ __align__(16) unsigned short Wsb[3][2048];     // 3 x 4 KB eighth buffers
    __shared__ int sIdx[IDX_CAP];                             // 1.5 KB (sorted values)
    __shared__ int sSelf[64];
    __shared__ int rcnt[64], rbase[64], rpos[64];
    const int tid = threadIdx.x;
    const int row0 = blockIdx.x * 64;
    const int wave = tid >> 6, lane = tid & 63;

    // prefetch W1 eighths 0,1: hidden under the gather, drained by its barrier
    stage8(W1t, 0, Wsb[0], wave, lane);
    stage8(W1t, 1, Wsb[1], wave, lane);

    const int blk = blockIdx.x;
    const int bstart = (blk == 0) ? 0 : blkOff[blk - 1];
    const int cnt = blkOff[blk] - bstart;

    if (tid < 64) sSelf[tid] = CONV0 ? self_idx[row0 + tid] : row0 + tid;
    __syncthreads();

    // ---- self term: thread (rb,g) owns rows rb+16i ----
    const float e = 1.0f + eps_ptr[0];
    const int g = tid & 15;
    const int rb = tid >> 4;        // 0..15
    float a[4][8];
#pragma unroll
    for (int i = 0; i < 4; ++i) {
        int self = sSelf[rb + 16 * i];
        ushort8 u = *(const ushort8*)(tbl + (size_t)self * 128 + g * 8);
#pragma unroll
        for (int j = 0; j < 8; ++j) a[i][j] = e * bf2f(u[j]);
    }

    // ---- chunked: LDS counting sort by row, then interleaved gather ----
    int done = 0;
    while (done < cnt) {
        const int chunk = (cnt - done < IDX_CAP) ? (cnt - done) : IDX_CAP;
        if (tid < 64) rcnt[tid] = 0;
        __syncthreads();
        int e0 = -1, e1 = -1;
        if (tid < chunk) {
            int2 pk = edgePk[bstart + done + tid];
            e0 = CONV0 ? pk.y : pk.x;
            atomicAdd(&rcnt[e0 >> PKSHIFT], 1);
        }
        if (tid + 256 < chunk) {
            int2 pk = edgePk[bstart + done + tid + 256];
            e1 = CONV0 ? pk.y : pk.x;
            atomicAdd(&rcnt[e1 >> PKSHIFT], 1);
        }
        __syncthreads();
        if (tid < 64) {            // wave-0 exclusive prefix over 64 row counts
            int c = rcnt[tid];
            int s = c;
#pragma unroll
            for (int d = 1; d < 64; d <<= 1) {
                int t = __shfl_up(s, d, 64);
                if (tid >= d) s += t;
            }
            rbase[tid] = s - c;
            rpos[tid]  = s - c;
        }
        __syncthreads();
        if (e0 >= 0) { int p = atomicAdd(&rpos[e0 >> PKSHIFT], 1); sIdx[p] = e0 & PKMASK; }
        if (e1 >= 0) { int p = atomicAdd(&rpos[e1 >> PKSHIFT], 1); sIdx[p] = e1 & PKMASK; }
        __syncthreads();           // rpos[r] now == end of row r

        int st[4], en[4];
#pragma unroll
        for (int i = 0; i < 4; ++i) {
            int r = rb + 16 * i;
            st[i] = rbase[r]; en[i] = rpos[r];
        }
        const int cmax = chunk - 1;
        while (__ballot((st[0] < en[0]) | (st[1] < en[1]) |
                        (st[2] < en[2]) | (st[3] < en[3]))) {
            ushort8 v[4];
#pragma unroll
            for (int i = 0; i < 4; ++i) {
                int p = st[i] < cmax ? st[i] : cmax;   // clamped: always valid
                int idx = sIdx[p];
                v[i] = *(const ushort8*)(tbl + (size_t)idx * 128 + g * 8);
            }
#pragma unroll
            for (int i = 0; i < 4; ++i) {
                if (st[i] < en[i]) {
#pragma unroll
                    for (int j = 0; j < 8; ++j) a[i][j] += bf2f(v[i][j]);
                    st[i]++;
                }
            }
        }
        done += chunk;
        __syncthreads();           // protect sIdx/rcnt for next chunk
    }

#pragma unroll
    for (int i = 0; i < 4; ++i) {
        ushort8 xv;
#pragma unroll
        for (int j = 0; j < 8; ++j) xv[j] = f2bf(a[i][j]);
        *(ushort8*)xs_addr(Xs, g, rb + 16 * i) = xv;
    }
    __syncthreads();   // Xs ready; drains vmcnt(0): gather loads + W1 e0,e1 DMAs

    const int ln = lane & 15, quad = lane >> 4;
    const int row = wave * 16 + ln;   // wave-private X/H row (4 waves x 16 = 64)

    // hoist X fragments (wave reads only its own rows)
    short8 xb[4];
#pragma unroll
    for (int kc = 0; kc < 4; ++kc)
        xb[kc] = *(const short8*)xs_addr(Xs, kc * 4 + quad, row);

    f32x4 acc[8];
#pragma unroll
    for (int t = 0; t < 8; ++t) acc[t] = (f32x4){0.f, 0.f, 0.f, 0.f};

    // ---- GEMM 1 (global steps 0..7): prefetch step+2 (7,8,9 -> W2 e0,e1) ----
#pragma unroll
    for (int s = 0; s < 8; ++s) {
        int pf = s + 2;
        stage8(pf < 8 ? W1t : W2t, pf & 7, Wsb[pf % 3], wave, lane);
        mfma4(Wsb[s % 3], xb, acc[s], quad, ln);
        pipe_barrier<1>();   // retires DMA(s+1); DMA(s+2) stays in flight
    }

    // h = relu(acc + b1) -> Xs (own rows only; same-wave DS ordering suffices)
    {
        const int j0 = (quad & 1) * 4;
#pragma unroll
        for (int t = 0; t < 8; ++t) {
            int p0 = t * 16 + quad * 4;
            f32x4 bv = *(const f32x4*)(b1 + p0);
            u16x4 hp;
#pragma unroll
            for (int i = 0; i < 4; ++i) hp[i] = f2bf(fmaxf(acc[t][i] + bv[i], 0.f));
            *(u16x4*)((char*)xs_addr(Xs, p0 >> 3, row) + j0 * 2) = hp;
        }
    }

    // hoist H fragments (own rows, written by own wave's lanes)
    short8 hb[4];
#pragma unroll
    for (int kc = 0; kc < 4; ++kc)
        hb[kc] = *(const short8*)xs_addr(Xs, kc * 4 + quad, row);

#pragma unroll
    for (int t = 0; t < 8; ++t) acc[t] = (f32x4){0.f, 0.f, 0.f, 0.f};

    // ---- GEMM 2 (global steps 8..15): buffers for steps 8,9 already in flight ----
#pragma unroll
    for (int f = 0; f < 8; ++f) {
        if (f < 6) stage8(W2t, f + 2, Wsb[(f + 10) % 3], wave, lane);
        mfma4(Wsb[(f + 8) % 3], hb, acc[f], quad, ln);
        if (f < 6)      pipe_barrier<1>();
        else if (f == 6) pipe_barrier<0>();   // drain last DMA (step 15) exactly once
    }

    // epilogue: lane holds out[orow][n0..n0+3] -> 8B stores; CONV0=false rows
    // land at pool rank (full 256B per row -> no write amplification)
    const int m = row0 + row;
    const int orow = CONV0 ? m : outIdx[m];
    unsigned short* obase = out + (size_t)orow * 128;
#pragma unroll
    for (int t = 0; t < 8; ++t) {
        int n0 = t * 16 + quad * 4;
        f32x4 bv = *(const f32x4*)(b2 + n0);
        f32x4 gv = *(const f32x4*)(gam + n0);
        f32x4 tv = *(const f32x4*)(bet + n0);
        u16x4 op;
#pragma unroll
        for (int i = 0; i < 4; ++i) {
            float h = acc[t][i] + bv[i];
            h = gv[i] * h * INV_STD + tv[i];
            if (CONV0) h = fmaxf(h, 0.f);
            op[i] = f2bf(h);
        }
        *(u16x4*)(obase + n0) = op;
    }
}

// ---------------- embedding GEMM (f32 in): out = in @ W + b ----------------
__global__ __launch_bounds__(256) void gemm_embed(
    const float* __restrict__ in, const unsigned short* __restrict__ Wt,
    const float* __restrict__ bias, unsigned short* __restrict__ out_bf, int rows)
{
    __shared__ __align__(16) unsigned short Xs[16 * 64 * 8];
    __shared__ __align__(16) unsigned short Ws[16 * 128 * 8];
    int tid = threadIdx.x;
    int row0 = blockIdx.x * 64;
#pragma unroll
    for (int i = 0; i < 8; ++i) {
        int chunk = tid + i * 256;
        int n = chunk >> 4, g = chunk & 15;
        *(short8*)(Ws + (g * 128 + n) * 8) =
            *(const short8*)(Wt + (n >> 4) * 2048 + g * 128 + (n & 15) * 8);
    }
#pragma unroll
    for (int i = 0; i < 4; ++i) {
        int chunk = tid + i * 256;
        int r = chunk >> 4, g = chunk & 15;
        int gr = row0 + r;
        ushort8 v;
        if (gr < rows) {
            const float* p = in + (size_t)gr * 128 + g * 8;
            f32x4 a0 = *(const f32x4*)p;
            f32x4 a1 = *(const f32x4*)(p + 4);
#pragma unroll
            for (int j = 0; j < 4; ++j) { v[j] = f2bf(a0[j]); v[4 + j] = f2bf(a1[j]); }
        } else {
#pragma unroll
            for (int j = 0; j < 8; ++j) v[j] = 0;
        }
        *(ushort8*)(Xs + (g * 64 + r) * 8) = v;
    }
    __syncthreads();
    int wave = tid >> 6, lane = tid & 63;
    int m0 = wave * 16;
    int ln = lane & 15, quad = lane >> 4;
    f32x4 acc[8];
#pragma unroll
    for (int t = 0; t < 8; ++t) acc[t] = (f32x4){0.f, 0.f, 0.f, 0.f};
#pragma unroll
    for (int kc = 0; kc < 4; ++kc) {
        int g = kc * 4 + quad;
        short8 a = *(const short8*)(Xs + (g * 64 + m0 + ln) * 8);
#pragma unroll
        for (int t = 0; t < 8; ++t) {
            short8 b = *(const short8*)(Ws + (g * 128 + t * 16 + ln) * 8);
            acc[t] = __builtin_amdgcn_mfma_f32_16x16x32_bf16(a, b, acc[t], 0, 0, 0);
        }
    }
#pragma unroll
    for (int t = 0; t < 8; ++t) {
        int col = t * 16 + ln;
        float bi = bias[col];
#pragma unroll
        for (int i = 0; i < 4; ++i) {
            int gr = row0 + m0 + quad * 4 + i;
            if (gr < rows) out_bf[(size_t)gr * 128 + col] = f2bf(acc[t][i] + bi);
        }
    }
}

// ---------------- y projection (embedding layer only) ----------------
__global__ __launch_bounds__(256) void proj_y0(
    const unsigned short* __restrict__ nx, const float* __restrict__ Wp,
    float* __restrict__ y, int rows)
{
    __shared__ float Wl[HID * NCLS];
    for (int i = threadIdx.x; i < HID * NCLS; i += 256) Wl[i] = Wp[i];
    __syncthreads();
    int r = blockIdx.x * 256 + threadIdx.x;
    if (r >= rows) return;
    float acc[NCLS];
#pragma unroll
    for (int c = 0; c < NCLS; ++c) acc[c] = 0.f;
    const unsigned short* xp = nx + (size_t)r * 128;
#pragma unroll 4
    for (int g = 0; g < 16; ++g) {
        ushort8 u = *(const ushort8*)(xp + g * 8);
#pragma unroll
        for (int j = 0; j < 8; ++j) {
            float xv = bf2f(u[j]);
            const float* w = Wl + (g * 8 + j) * NCLS;
#pragma unroll
            for (int c = 0; c < NCLS; ++c) acc[c] += xv * w[c];
        }
    }
    float* yp = y + (size_t)r * NCLS;
#pragma unroll
    for (int c = 0; c < NCLS; ++c) yp[c] = acc[c];
}

// ---------------- score scatter: score[b][:] += y[ori[m]][:] ----------------
__global__ __launch_bounds__(256) void score_scatter(
    const float* __restrict__ y, const int* __restrict__ ori,
    const int* __restrict__ batch, float* __restrict__ score)
{
    __shared__ float sc[NBATCH * NCLS];
    for (int i = threadIdx.x; i < NBATCH * NCLS; i += 256) sc[i] = 0.f;
    __syncthreads();
    int stride = gridDim.x * 256;
    for (int m = blockIdx.x * 256 + threadIdx.x; m < M_COPIES; m += stride) {
        int r = ori[m], b = batch[m];
        const float* yp = y + (size_t)r * NCLS;
#pragma unroll
        for (int c = 0; c < NCLS; ++c)
            __hip_atomic_fetch_add(&sc[b * NCLS + c], yp[c],
                                   __ATOMIC_RELAXED, __HIP_MEMORY_SCOPE_WORKGROUP);
    }
    __syncthreads();
    for (int i = threadIdx.x; i < NBATCH * NCLS; i += 256) gatomic_add(score + i, sc[i]);
}

__global__ void score_final(const float* __restrict__ score, const float* __restrict__ bp,
                            float* __restrict__ out)
{
    int t = threadIdx.x;
    if (t >= NBATCH * NCLS) return;
    int c = t % NCLS;
    out[t] = score[t] + bp[c] + bp[NCLS + c] + bp[2 * NCLS + c];
}

__global__ void fill_sentinel(float* out, int n, float enc) {
    int t = blockIdx.x * 64 + threadIdx.x;
    if (t < n) out[t] = enc;
}

// ---------------- entry ----------------
extern "C" void kernel_launch(void* const* d_in, const int* in_sizes, int n_in,
                              void* d_out, int out_size, void* d_ws, size_t ws_size,
                              hipStream_t stream) {
    const float* x_N    = (const float*)d_in[0];
    const float* We     = (const float*)d_in[1];
    const float* be     = (const float*)d_in[2];
    const float* Wg     = (const float*)d_in[3];
    const float* bg     = (const float*)d_in[4];
    const float* eps_g  = (const float*)d_in[5];
    const float* gam    = (const float*)d_in[6];
    const float* bet    = (const float*)d_in[7];
    const float* Wp     = (const float*)d_in[8];
    const float* bp     = (const float*)d_in[9];
    const int* ori_node = (const int*)d_in[10];
    const int* node2edge= (const int*)d_in[11];
    const int* eiN      = (const int*)d_in[12];
    const int* ori_edge = (const int*)d_in[13];
    const int* edge2node= (const int*)d_in[14];
    const int* eiE      = (const int*)d_in[15];
    const int* batch    = (const int*)d_in[16];

    const int NBLK = M_COPIES / 64;            // 6250 conv blocks / CSR regions

    char* p = (char*)d_ws;
    auto take = [&](size_t n) { char* r = p; p += (n + 255) & ~(size_t)255; return r; };
    unsigned short* Wt  = (unsigned short*)take((size_t)17 * 16384 * 2);
    unsigned short* Xb  = (unsigned short*)take((size_t)M_COPIES * 128 * 2);
    unsigned short* Xb2 = (unsigned short*)take((size_t)M_COPIES * 128 * 2);
    unsigned short* nx  = (unsigned short*)take((size_t)N_NODES * 128 * 2);
    unsigned short* ex  = (unsigned short*)take((size_t)N_EDGES * 128 * 2);
    float* y            = (float*)take((size_t)N_NODES * NCLS * 4);
    float* score        = (float*)take((size_t)NBATCH * NCLS * 4);
    // blkN/blkE in ONE allocation: NBLK*4 is not 256-aligned, and the memset
    // below must cover both arrays exactly (R4 crash lesson).
    int* blkN           = (int*)take((size_t)2 * NBLK * 4);
    int* blkE           = blkN + NBLK;
    int* off_n2e        = (int*)take((size_t)N_EDGES * 4);    // n2e/e2n contiguous
    int* off_e2n        = (int*)take((size_t)N_NODES * 4);
    int2* pkN           = (int2*)take((size_t)L_EDGES * 8);
    int2* pkE           = (int2*)take((size_t)L_EDGES * 8);
    int* rk_n2e         = (int*)take((size_t)M_COPIES * 4);
    int* rk_e2n         = (int*)take((size_t)M_COPIES * 4);
    int* part           = (int*)take((size_t)8192 * 4);
    size_t need = (size_t)(p - (char*)d_ws);
    if (need > ws_size) {
        fill_sentinel<<<(out_size + 63) / 64, 64, 0, stream>>>(
            (float*)d_out, out_size, 1.0e9f + (float)ws_size);
        return;
    }

    prep_w<<<1088, 256, 0, stream>>>(We, Wg, Wt);
    (void)hipMemsetAsync(score, 0, (size_t)NBATCH * NCLS * 4, stream);

    // ---- CSR builds ----
    const int NB_M = (M_COPIES + 255) / 256;   // 1563
    const int NB_L = (L_EDGES + 255) / 256;    // 3125
    const int NB_N = (N_NODES + 255) / 256;    // 196
    const int NB_B = (NBLK + 255) / 256;       // 25
    int* partB = part + 4096;

    // edge CSRs at block (64-row) granularity
    (void)hipMemsetAsync(blkN, 0, (size_t)2 * NBLK * 4, stream);   // one contiguous span
    hist2_k<<<NB_L, 256, 0, stream>>>(eiN + L_EDGES, L_EDGES, blkN,
                                      eiE + L_EDGES, L_EDGES, blkE, 6);
    scan1d_k<<<dim3(NB_B, 2), 256, 0, stream>>>(blkN, NBLK, part, blkE, NBLK, partB);
    scan2d_k<<<2, 256, 0, stream>>>(part, NB_B, partB, NB_B);
    scan3d_k<<<dim3(NB_B, 2), 256, 0, stream>>>(blkN, NBLK, part, blkE, NBLK, partB);
    fill_edgeblk2_k<<<NB_L, 256, 0, stream>>>(
        eiN, eiN + L_EDGES, ori_node, L_EDGES, blkN, pkN,
        eiE, eiE + L_EDGES, ori_edge, L_EDGES, blkE, pkE);

    // pool CSRs (off_n2e over N_EDGES segs, off_e2n over N_NODES segs)
    (void)hipMemsetAsync(off_n2e, 0,
        (size_t)((char*)off_e2n - (char*)off_n2e) + (size_t)N_NODES * 4, stream);
    hist2_k<<<NB_M, 256, 0, stream>>>(node2edge, M_COPIES, off_n2e,
                                      edge2node, M_COPIES, off_e2n, 0);
    scan1d_k<<<dim3(NB_N, 2), 256, 0, stream>>>(off_n2e, N_EDGES, part, off_e2n, N_NODES, partB);
    scan2d_k<<<2, 256, 0, stream>>>(part, (N_EDGES + 255) / 256, partB, NB_N);
    scan3d_k<<<dim3(NB_N, 2), 256, 0, stream>>>(off_n2e, N_EDGES, part, off_e2n, N_NODES, partB);
    fill_pool2_k<<<NB_M, 256, 0, stream>>>(node2edge, M_COPIES, off_n2e, rk_n2e,
                                           edge2node, M_COPIES, off_e2n, rk_e2n);

    gemm_embed<<<(N_NODES + 63) / 64, 256, 0, stream>>>(x_N, Wt, be, nx, N_NODES);
    proj_y0<<<(N_NODES + 255) / 256, 256, 0, stream>>>(nx, Wp, y, N_NODES);

    for (int layer = 0; layer < 2; ++layer) {
        for (int dir = 0; dir < 2; ++dir) {
            int cj0 = layer * 4 + dir * 2;
            int cj1 = cj0 + 1;
            const unsigned short* base = (dir == 0) ? nx : ex;
            const int* selfI = (dir == 0) ? ori_node : ori_edge;
            const int* blkD  = (dir == 0) ? blkN : blkE;
            const int2* pkD  = (dir == 0) ? pkN : pkE;
            const int* rkD   = (dir == 0) ? rk_n2e : rk_e2n;

            fused_conv<true><<<NBLK, 256, 0, stream>>>(
                base, selfI, blkD, pkD, nullptr, eps_g + cj0,
                Wt + (size_t)(1 + cj0 * 2) * 16384, bg + (cj0 * 2) * 128,
                Wt + (size_t)(1 + cj0 * 2 + 1) * 16384, bg + (cj0 * 2 + 1) * 128,
                gam + cj0 * 128, bet + cj0 * 128, Xb);
            fused_conv<false><<<NBLK, 256, 0, stream>>>(
                Xb, nullptr, blkD, pkD, rkD, eps_g + cj1,
                Wt + (size_t)(1 + cj1 * 2) * 16384, bg + (cj1 * 2) * 128,
                Wt + (size_t)(1 + cj1 * 2 + 1) * 16384, bg + (cj1 * 2 + 1) * 128,
                gam + cj1 * 128, bet + cj1 * 128, Xb2);
            if (dir == 0) {
                segsum_pool<false><<<(N_EDGES + 3) / 4, 256, 0, stream>>>(
                    Xb2, off_n2e, ex, N_EDGES, nullptr, nullptr);
            } else {
                segsum_pool<true><<<(N_NODES + 3) / 4, 256, 0, stream>>>(
                    Xb2, off_e2n, nx, N_NODES,
                    Wp + (size_t)(layer + 1) * HID * NCLS, y);
            }
        }
    }
    score_scatter<<<256, 256, 0, stream>>>(y, ori_node, batch, score);
    score_final<<<1, 320, 0, stream>>>(score, bp, (float*)d_out);
}

// Round 9
// 1346.433 us; speedup vs baseline: 1.0485x; 1.0485x over previous
//
#include <hip/hip_runtime.h>
#include <hip/hip_bf16.h>

// ---------------- problem constants ----------------
#define HID 128
static const int N_NODES = 50000;
static const int N_EDGES = 20000;
static const int M_COPIES = 400000;
static const int L_EDGES = 800000;
static const int NBATCH = 32;
static const int NCLS = 10;
#define INV_STD 0.9999950000374997f   // 1/sqrt(1+1e-5)
#define IDX_CAP 384                   // per-chunk item cap (block avg 128)
#define PKSHIFT 19                    // packed entry: (rloc<<19)|val, val<2^19
#define PKMASK  0x7FFFF

typedef __attribute__((ext_vector_type(4))) float f32x4;
typedef __attribute__((ext_vector_type(8))) short short8;      // 8 bf16 lanes
typedef __attribute__((ext_vector_type(8))) unsigned short ushort8;
typedef __attribute__((ext_vector_type(4))) unsigned short u16x4;  // 'ushort4' collides with HIP header

__device__ __forceinline__ float bf2f(unsigned short u) {
    union { unsigned u; float f; } v; v.u = ((unsigned)u) << 16; return v.f;
}
__device__ __forceinline__ unsigned short f2bf(float f) {
    union { float f; unsigned u; } v; v.f = f;
    unsigned r = v.u + 0x7FFFu + ((v.u >> 16) & 1u);   // RNE
    return (unsigned short)(r >> 16);
}
__device__ __forceinline__ void gatomic_add(float* p, float v) {
    unsafeAtomicAdd(p, v);
}

// Swizzled Xs addressing: logical [chunk c][row r][8 bf16], 16 B per (c,r).
// byte = (c*1024 + r*16) ^ ((c&7)<<4) -> gather writes (c fast-varying across
// lanes) land on 8 distinct 16B slots instead of 1 (proven: conflicts 2.88e7->8e5).
__device__ __forceinline__ unsigned short* xs_addr(unsigned short* Xs, int c, int r) {
    int byte = ((c * 64 + r) * 16) ^ ((c & 7) << 4);
    return (unsigned short*)((char*)Xs + byte);
}

// Async DMA of one wave's 1KB quarter of a 4KB W-eighth into LDS (linear copy
// from the eighth-linear Wt image: conflict-free writes, no VGPR round trip).
__device__ __forceinline__ void stage8(const unsigned short* __restrict__ Wmat, int e,
                                       unsigned short* buf, int wave, int lane) {
    const char* g = (const char*)Wmat + ((size_t)e << 12) + (wave << 10) + (lane << 4);
    char* l = (char*)buf + (wave << 10);
    __builtin_amdgcn_global_load_lds(
        (const __attribute__((address_space(1))) unsigned int*)g,
        (__attribute__((address_space(3))) unsigned int*)l,
        16, 0, 0);
}

// Counted-vmcnt barrier (T4): keep DMAs in flight ACROSS the barrier.
// vmem ledger in the GEMM loops is exact: only stage8 DMAs are outstanding
// (gather-phase loads are drained by the gather-end __syncthreads).
template<int N>
__device__ __forceinline__ void pipe_barrier() {
    if constexpr (N == 0) asm volatile("s_waitcnt vmcnt(0)" ::: "memory");
    else                  asm volatile("s_waitcnt vmcnt(1)" ::: "memory");
    __builtin_amdgcn_s_barrier();
    asm volatile("" ::: "memory");
}

// 4 chained MFMAs: one eighth (16 out-channels) x full K for this wave's rows.
__device__ __forceinline__ void mfma4(const unsigned short* Ws, const short8* xv,
                                      f32x4& a, int quad, int ln) {
#pragma unroll
    for (int kc = 0; kc < 4; ++kc) {
        short8 wa = *(const short8*)(Ws + (((kc * 4 + quad) * 16) + ln) * 8);
        a = __builtin_amdgcn_mfma_f32_16x16x32_bf16(wa, xv[kc], a, 0, 0, 0);
    }
}

// ---------------- weight prep: eighth-linear layout ----------------
// Wt[mat] is 8 eighths x 2048 shorts; within an eighth, chunk (gg,n) at
// offset (gg*16+n)*8 holds W[k=gg*8..gg*8+7][col=h*16+n] -> LDS image == global.
__global__ __launch_bounds__(256) void prep_w(const float* __restrict__ We,
                                              const float* __restrict__ Wg,
                                              unsigned short* __restrict__ Wt) {
    int t = blockIdx.x * 256 + threadIdx.x;       // 17*16384
    if (t >= 17 * 16384) return;
    int mat = t >> 14, rem = t & 16383;
    int h = rem >> 11, r2 = rem & 2047;
    int gg = r2 >> 7, r3 = r2 & 127;
    int n = r3 >> 3, j = r3 & 7;
    int k = gg * 8 + j, col = h * 16 + n;
    const float* src = (mat == 0) ? We : (Wg + (size_t)(mat - 1) * 16384);
    Wt[t] = f2bf(src[k * 128 + col]);
}

// ---------------- CSR build ----------------
__global__ __launch_bounds__(256) void hist2_k(
    const int* __restrict__ iA, int nA, int* __restrict__ cA,
    const int* __restrict__ iB, int nB, int* __restrict__ cB, int shift) {
    int t = blockIdx.x * 256 + threadIdx.x;
    if (t < nA) atomicAdd(&cA[iA[t] >> shift], 1);
    if (t < nB) atomicAdd(&cB[iB[t] >> shift], 1);
}

__global__ __launch_bounds__(256) void scan1d_k(
    int* __restrict__ a0, int n0, int* __restrict__ p0,
    int* __restrict__ a1, int n1, int* __restrict__ p1) {
    int* a    = blockIdx.y ? a1 : a0;
    int n     = blockIdx.y ? n1 : n0;
    int* part = blockIdx.y ? p1 : p0;
    if ((int)(blockIdx.x * 256) >= n) return;   // uniform per block
    __shared__ int s[256];
    int i = blockIdx.x * 256 + threadIdx.x;
    int v = (i < n) ? a[i] : 0;
    s[threadIdx.x] = v;
    __syncthreads();
#pragma unroll
    for (int d = 1; d < 256; d <<= 1) {
        int t = (threadIdx.x >= d) ? s[threadIdx.x - d] : 0;
        __syncthreads();
        s[threadIdx.x] += t;
        __syncthreads();
    }
    if (i < n) a[i] = s[threadIdx.x] - v;
    if (threadIdx.x == 255) part[blockIdx.x] = s[255];
}

__global__ __launch_bounds__(256) void scan2d_k(
    int* __restrict__ p0, int nb0, int* __restrict__ p1, int nb1) {
    int* part = blockIdx.x ? p1 : p0;
    int nb    = blockIdx.x ? nb1 : nb0;
    __shared__ int s[256];
    __shared__ int carry;
    if (threadIdx.x == 0) carry = 0;
    __syncthreads();
    for (int base = 0; base < nb; base += 256) {
        int i = base + threadIdx.x;
        int v = (i < nb) ? part[i] : 0;
        s[threadIdx.x] = v;
        __syncthreads();
#pragma unroll
        for (int d = 1; d < 256; d <<= 1) {
            int t = (threadIdx.x >= d) ? s[threadIdx.x - d] : 0;
            __syncthreads();
            s[threadIdx.x] += t;
            __syncthreads();
        }
        if (i < nb) part[i] = carry + s[threadIdx.x] - v;
        __syncthreads();
        if (threadIdx.x == 0) carry += s[255];
        __syncthreads();
    }
}

__global__ __launch_bounds__(256) void scan3d_k(
    int* __restrict__ a0, int n0, const int* __restrict__ p0,
    int* __restrict__ a1, int n1, const int* __restrict__ p1) {
    int* a          = blockIdx.y ? a1 : a0;
    int n           = blockIdx.y ? n1 : n0;
    const int* part = blockIdx.y ? p1 : p0;
    int i = blockIdx.x * 256 + threadIdx.x;
    if (i < n) a[i] += part[blockIdx.x];
}

// Block-granular edge fill: region key = dst>>6 (6250 regions of 64 rows).
// ONE packed int2 store per edge: {.x=(rloc<<19)|src, .y=(rloc<<19)|remap[src]}.
__global__ __launch_bounds__(256) void fill_edgeblk2_k(
    const int* __restrict__ sA, const int* __restrict__ dA, const int* __restrict__ rA,
    int nA, int* __restrict__ oA, int2* __restrict__ pkA,
    const int* __restrict__ sB, const int* __restrict__ dB, const int* __restrict__ rB,
    int nB, int* __restrict__ oB, int2* __restrict__ pkB) {
    int t = blockIdx.x * 256 + threadIdx.x;
    if (t < nA) {
        int d = dA[t]; int pos = atomicAdd(&oA[d >> 6], 1);
        int s = sA[t]; int rl = (d & 63) << PKSHIFT;
        pkA[pos] = (int2){rl | s, rl | rA[s]};
    }
    if (t < nB) {
        int d = dB[t]; int pos = atomicAdd(&oB[d >> 6], 1);
        int s = sB[t]; int rl = (d & 63) << PKSHIFT;
        pkB[pos] = (int2){rl | s, rl | rB[s]};
    }
}

__global__ __launch_bounds__(256) void fill_pool2_k(
    const int* __restrict__ gA, int nA, int* __restrict__ oA, int* __restrict__ itA,
    const int* __restrict__ gB, int nB, int* __restrict__ oB, int* __restrict__ itB) {
    int t = blockIdx.x * 256 + threadIdx.x;
    if (t < nA) { int pos = atomicAdd(&oA[gA[t]], 1); itA[pos] = t; }
    if (t < nB) { int pos = atomicAdd(&oB[gB[t]], 1); itB[pos] = t; }
}

// ---------------- pool segment sum: wave-per-segment ----------------
// lane (g=lane&15, sub=lane>>4); unrolled x2: 8 random-row loads in flight.
__global__ __launch_bounds__(256) void segsum_pool(
    const unsigned short* __restrict__ tbl, const int* __restrict__ off,
    const int* __restrict__ items, unsigned short* __restrict__ out, int nseg)
{
    int wave = threadIdx.x >> 6, lane = threadIdx.x & 63;
    int seg = blockIdx.x * 4 + wave;
    if (seg >= nseg) return;
    int start = (seg == 0) ? 0 : off[seg - 1];
    int end = off[seg];
    int g = lane & 15, sub = lane >> 4;
    float a[8] = {0.f, 0.f, 0.f, 0.f, 0.f, 0.f, 0.f, 0.f};
    int p = start + sub;
    for (; p + 4 < end; p += 8) {
        int r0 = items[p], r1 = items[p + 4];
        ushort8 v0 = *(const ushort8*)(tbl + (size_t)r0 * 128 + g * 8);
        ushort8 v1 = *(const ushort8*)(tbl + (size_t)r1 * 128 + g * 8);
#pragma unroll
        for (int j = 0; j < 8; ++j) a[j] += bf2f(v0[j]) + bf2f(v1[j]);
    }
    if (p < end) {
        int r = items[p];
        ushort8 v = *(const ushort8*)(tbl + (size_t)r * 128 + g * 8);
#pragma unroll
        for (int j = 0; j < 8; ++j) a[j] += bf2f(v[j]);
    }
#pragma unroll
    for (int j = 0; j < 8; ++j) {
        a[j] += __shfl_xor(a[j], 16, 64);
        a[j] += __shfl_xor(a[j], 32, 64);
    }
    if (sub == 0) {
        ushort8 ov;
#pragma unroll
        for (int j = 0; j < 8; ++j) ov[j] = f2bf(fmaxf(a[j], 0.f));
        *(ushort8*)(out + (size_t)seg * 128 + g * 8) = ov;
    }
}

// ---------------- fused GIN conv: 256 thr / 64 rows ----------------
// gather-segsum + linear1+ReLU + linear2+BN(+ReLU).
// R5-proven configuration — the measured local optimum (115.5 us, WRITE 100MB):
//   * 5 blocks/CU (6 -> launch_bounds VGPR cap 42 < 48 needed -> spill, R6)
//   * 1-wide 4-row-interleaved ballot gather (2-wide -> +16 VGPR -> spill, R7)
//   * linear epilogue (pool-rank scatter -> partial-line RMW traffic, R8)
//   * Wsb[3] + counted vmcnt(1) pipeline, block-granular CSR + LDS counting sort
template<bool CONV0>
__global__ __launch_bounds__(256, 5) void fused_conv(
    const unsigned short* __restrict__ tbl,
    const int* __restrict__ self_idx,
    const int* __restrict__ blkOff, const int2* __restrict__ edgePk,
    const float* __restrict__ eps_ptr,
    const unsigned short* __restrict__ W1t, const float* __restrict__ b1,
    const unsigned short* __restrict__ W2t, const float* __restrict__ b2,
    const float* __restrict__ gam, const float* __restrict__ bet,
    unsigned short* __restrict__ out)
{
    __shared__ __align__(16) unsigned short Xs[16 * 64 * 8];  // 16 KB, swizzled
    __shared__ __align__(16) unsigned short Wsb[3][2048];     // 3 x 4 KB eighth buffers
    __shared__ int sIdx[IDX_CAP];                             // 1.5 KB (sorted values)
    __shared__ int sSelf[64];
    __shared__ int rcnt[64], rbase[64], rpos[64];
    const int tid = threadIdx.x;
    const int row0 = blockIdx.x * 64;
    const int wave = tid >> 6, lane = tid & 63;

    // prefetch W1 eighths 0,1: hidden under the gather, drained by its barrier
    stage8(W1t, 0, Wsb[0], wave, lane);
    stage8(W1t, 1, Wsb[1], wave, lane);

    const int blk = blockIdx.x;
    const int bstart = (blk == 0) ? 0 : blkOff[blk - 1];
    const int cnt = blkOff[blk] - bstart;

    if (tid < 64) sSelf[tid] = CONV0 ? self_idx[row0 + tid] : row0 + tid;
    __syncthreads();

    // ---- self term: thread (rb,g) owns rows rb+16i ----
    const float e = 1.0f + eps_ptr[0];
    const int g = tid & 15;
    const int rb = tid >> 4;        // 0..15
    float a[4][8];
#pragma unroll
    for (int i = 0; i < 4; ++i) {
        int self = sSelf[rb + 16 * i];
        ushort8 u = *(const ushort8*)(tbl + (size_t)self * 128 + g * 8);
#pragma unroll
        for (int j = 0; j < 8; ++j) a[i][j] = e * bf2f(u[j]);
    }

    // ---- chunked: LDS counting sort by row, then interleaved gather ----
    int done = 0;
    while (done < cnt) {
        const int chunk = (cnt - done < IDX_CAP) ? (cnt - done) : IDX_CAP;
        if (tid < 64) rcnt[tid] = 0;
        __syncthreads();
        int e0 = -1, e1 = -1;
        if (tid < chunk) {
            int2 pk = edgePk[bstart + done + tid];
            e0 = CONV0 ? pk.y : pk.x;
            atomicAdd(&rcnt[e0 >> PKSHIFT], 1);
        }
        if (tid + 256 < chunk) {
            int2 pk = edgePk[bstart + done + tid + 256];
            e1 = CONV0 ? pk.y : pk.x;
            atomicAdd(&rcnt[e1 >> PKSHIFT], 1);
        }
        __syncthreads();
        if (tid < 64) {            // wave-0 exclusive prefix over 64 row counts
            int c = rcnt[tid];
            int s = c;
#pragma unroll
            for (int d = 1; d < 64; d <<= 1) {
                int t = __shfl_up(s, d, 64);
                if (tid >= d) s += t;
            }
            rbase[tid] = s - c;
            rpos[tid]  = s - c;
        }
        __syncthreads();
        if (e0 >= 0) { int p = atomicAdd(&rpos[e0 >> PKSHIFT], 1); sIdx[p] = e0 & PKMASK; }
        if (e1 >= 0) { int p = atomicAdd(&rpos[e1 >> PKSHIFT], 1); sIdx[p] = e1 & PKMASK; }
        __syncthreads();           // rpos[r] now == end of row r

        int st[4], en[4];
#pragma unroll
        for (int i = 0; i < 4; ++i) {
            int r = rb + 16 * i;
            st[i] = rbase[r]; en[i] = rpos[r];
        }
        const int cmax = chunk - 1;
        while (__ballot((st[0] < en[0]) | (st[1] < en[1]) |
                        (st[2] < en[2]) | (st[3] < en[3]))) {
            ushort8 v[4];
#pragma unroll
            for (int i = 0; i < 4; ++i) {
                int p = st[i] < cmax ? st[i] : cmax;   // clamped: always valid
                int idx = sIdx[p];
                v[i] = *(const ushort8*)(tbl + (size_t)idx * 128 + g * 8);
            }
#pragma unroll
            for (int i = 0; i < 4; ++i) {
                if (st[i] < en[i]) {
#pragma unroll
                    for (int j = 0; j < 8; ++j) a[i][j] += bf2f(v[i][j]);
                    st[i]++;
                }
            }
        }
        done += chunk;
        __syncthreads();           // protect sIdx/rcnt for next chunk
    }

#pragma unroll
    for (int i = 0; i < 4; ++i) {
        ushort8 xv;
#pragma unroll
        for (int j = 0; j < 8; ++j) xv[j] = f2bf(a[i][j]);
        *(ushort8*)xs_addr(Xs, g, rb + 16 * i) = xv;
    }
    __syncthreads();   // Xs ready; drains vmcnt(0): gather loads + W1 e0,e1 DMAs

    const int ln = lane & 15, quad = lane >> 4;
    const int row = wave * 16 + ln;   // wave-private X/H row (4 waves x 16 = 64)

    // hoist X fragments (wave reads only its own rows)
    short8 xb[4];
#pragma unroll
    for (int kc = 0; kc < 4; ++kc)
        xb[kc] = *(const short8*)xs_addr(Xs, kc * 4 + quad, row);

    f32x4 acc[8];
#pragma unroll
    for (int t = 0; t < 8; ++t) acc[t] = (f32x4){0.f, 0.f, 0.f, 0.f};

    // ---- GEMM 1 (global steps 0..7): prefetch step+2 (7,8,9 -> W2 e0,e1) ----
#pragma unroll
    for (int s = 0; s < 8; ++s) {
        int pf = s + 2;
        stage8(pf < 8 ? W1t : W2t, pf & 7, Wsb[pf % 3], wave, lane);
        mfma4(Wsb[s % 3], xb, acc[s], quad, ln);
        pipe_barrier<1>();   // retires DMA(s+1); DMA(s+2) stays in flight
    }

    // h = relu(acc + b1) -> Xs (own rows only; same-wave DS ordering suffices)
    {
        const int j0 = (quad & 1) * 4;
#pragma unroll
        for (int t = 0; t < 8; ++t) {
            int p0 = t * 16 + quad * 4;
            f32x4 bv = *(const f32x4*)(b1 + p0);
            u16x4 hp;
#pragma unroll
            for (int i = 0; i < 4; ++i) hp[i] = f2bf(fmaxf(acc[t][i] + bv[i], 0.f));
            *(u16x4*)((char*)xs_addr(Xs, p0 >> 3, row) + j0 * 2) = hp;
        }
    }

    // hoist H fragments (own rows, written by own wave's lanes)
    short8 hb[4];
#pragma unroll
    for (int kc = 0; kc < 4; ++kc)
        hb[kc] = *(const short8*)xs_addr(Xs, kc * 4 + quad, row);

#pragma unroll
    for (int t = 0; t < 8; ++t) acc[t] = (f32x4){0.f, 0.f, 0.f, 0.f};

    // ---- GEMM 2 (global steps 8..15): buffers for steps 8,9 already in flight ----
#pragma unroll
    for (int f = 0; f < 8; ++f) {
        if (f < 6) stage8(W2t, f + 2, Wsb[(f + 10) % 3], wave, lane);
        mfma4(Wsb[(f + 8) % 3], hb, acc[f], quad, ln);
        if (f < 6)      pipe_barrier<1>();
        else if (f == 6) pipe_barrier<0>();   // drain last DMA (step 15) exactly once
    }

    // epilogue: lane holds out[row0+row][n0..n0+3] -> 8B stores
    const int m = row0 + row;
#pragma unroll
    for (int t = 0; t < 8; ++t) {
        int n0 = t * 16 + quad * 4;
        f32x4 bv = *(const f32x4*)(b2 + n0);
        f32x4 gv = *(const f32x4*)(gam + n0);
        f32x4 tv = *(const f32x4*)(bet + n0);
        u16x4 op;
#pragma unroll
        for (int i = 0; i < 4; ++i) {
            float h = acc[t][i] + bv[i];
            h = gv[i] * h * INV_STD + tv[i];
            if (CONV0) h = fmaxf(h, 0.f);
            op[i] = f2bf(h);
        }
        *(u16x4*)(out + (size_t)m * 128 + n0) = op;
    }
}

// ---------------- embedding GEMM (f32 in): out = in @ W + b ----------------
__global__ __launch_bounds__(256) void gemm_embed(
    const float* __restrict__ in, const unsigned short* __restrict__ Wt,
    const float* __restrict__ bias, unsigned short* __restrict__ out_bf, int rows)
{
    __shared__ __align__(16) unsigned short Xs[16 * 64 * 8];
    __shared__ __align__(16) unsigned short Ws[16 * 128 * 8];
    int tid = threadIdx.x;
    int row0 = blockIdx.x * 64;
#pragma unroll
    for (int i = 0; i < 8; ++i) {
        int chunk = tid + i * 256;
        int n = chunk >> 4, g = chunk & 15;
        // source: eighth-linear Wt -> chunk (g, n) at (n>>4)*2048 + g*128 + (n&15)*8
        *(short8*)(Ws + (g * 128 + n) * 8) =
            *(const short8*)(Wt + (n >> 4) * 2048 + g * 128 + (n & 15) * 8);
    }
#pragma unroll
    for (int i = 0; i < 4; ++i) {
        int chunk = tid + i * 256;
        int r = chunk >> 4, g = chunk & 15;
        int gr = row0 + r;
        ushort8 v;
        if (gr < rows) {
            const float* p = in + (size_t)gr * 128 + g * 8;
            f32x4 a0 = *(const f32x4*)p;
            f32x4 a1 = *(const f32x4*)(p + 4);
#pragma unroll
            for (int j = 0; j < 4; ++j) { v[j] = f2bf(a0[j]); v[4 + j] = f2bf(a1[j]); }
        } else {
#pragma unroll
            for (int j = 0; j < 8; ++j) v[j] = 0;
        }
        *(ushort8*)(Xs + (g * 64 + r) * 8) = v;
    }
    __syncthreads();
    int wave = tid >> 6, lane = tid & 63;
    int m0 = wave * 16;
    int ln = lane & 15, quad = lane >> 4;
    f32x4 acc[8];
#pragma unroll
    for (int t = 0; t < 8; ++t) acc[t] = (f32x4){0.f, 0.f, 0.f, 0.f};
#pragma unroll
    for (int kc = 0; kc < 4; ++kc) {
        int g = kc * 4 + quad;
        short8 a = *(const short8*)(Xs + (g * 64 + m0 + ln) * 8);
#pragma unroll
        for (int t = 0; t < 8; ++t) {
            short8 b = *(const short8*)(Ws + (g * 128 + t * 16 + ln) * 8);
            acc[t] = __builtin_amdgcn_mfma_f32_16x16x32_bf16(a, b, acc[t], 0, 0, 0);
        }
    }
#pragma unroll
    for (int t = 0; t < 8; ++t) {
        int col = t * 16 + ln;
        float bi = bias[col];
#pragma unroll
        for (int i = 0; i < 4; ++i) {
            int gr = row0 + m0 + quad * 4 + i;
            if (gr < rows) out_bf[(size_t)gr * 128 + col] = f2bf(acc[t][i] + bi);
        }
    }
}

// ---------------- y projection: y[r][10] (+)= nx[r][:] @ Wp ----------------
template<bool ACCUM>
__global__ __launch_bounds__(256) void proj_y(
    const unsigned short* __restrict__ nx, const float* __restrict__ Wp,
    float* __restrict__ y, int rows)
{
    __shared__ float Wl[HID * NCLS];
    for (int i = threadIdx.x; i < HID * NCLS; i += 256) Wl[i] = Wp[i];
    __syncthreads();
    int r = blockIdx.x * 256 + threadIdx.x;
    if (r >= rows) return;
    float acc[NCLS];
#pragma unroll
    for (int c = 0; c < NCLS; ++c) acc[c] = 0.f;
    const unsigned short* xp = nx + (size_t)r * 128;
#pragma unroll 4
    for (int g = 0; g < 16; ++g) {
        ushort8 u = *(const ushort8*)(xp + g * 8);
#pragma unroll
        for (int j = 0; j < 8; ++j) {
            float xv = bf2f(u[j]);
            const float* w = Wl + (g * 8 + j) * NCLS;
#pragma unroll
            for (int c = 0; c < NCLS; ++c) acc[c] += xv * w[c];
        }
    }
    float* yp = y + (size_t)r * NCLS;
#pragma unroll
    for (int c = 0; c < NCLS; ++c) {
        if (ACCUM) yp[c] += acc[c];
        else yp[c] = acc[c];
    }
}

// ---------------- score scatter: score[b][:] += y[ori[m]][:] ----------------
__global__ __launch_bounds__(256) void score_scatter(
    const float* __restrict__ y, const int* __restrict__ ori,
    const int* __restrict__ batch, float* __restrict__ score)
{
    __shared__ float sc[NBATCH * NCLS];
    for (int i = threadIdx.x; i < NBATCH * NCLS; i += 256) sc[i] = 0.f;
    __syncthreads();
    int stride = gridDim.x * 256;
    for (int m = blockIdx.x * 256 + threadIdx.x; m < M_COPIES; m += stride) {
        int r = ori[m], b = batch[m];
        const float* yp = y + (size_t)r * NCLS;
#pragma unroll
        for (int c = 0; c < NCLS; ++c)
            __hip_atomic_fetch_add(&sc[b * NCLS + c], yp[c],
                                   __ATOMIC_RELAXED, __HIP_MEMORY_SCOPE_WORKGROUP);
    }
    __syncthreads();
    for (int i = threadIdx.x; i < NBATCH * NCLS; i += 256) gatomic_add(score + i, sc[i]);
}

__global__ void score_final(const float* __restrict__ score, const float* __restrict__ bp,
                            float* __restrict__ out)
{
    int t = threadIdx.x;
    if (t >= NBATCH * NCLS) return;
    int c = t % NCLS;
    out[t] = score[t] + bp[c] + bp[NCLS + c] + bp[2 * NCLS + c];
}

__global__ void fill_sentinel(float* out, int n, float enc) {
    int t = blockIdx.x * 64 + threadIdx.x;
    if (t < n) out[t] = enc;
}

// ---------------- entry ----------------
extern "C" void kernel_launch(void* const* d_in, const int* in_sizes, int n_in,
                              void* d_out, int out_size, void* d_ws, size_t ws_size,
                              hipStream_t stream) {
    const float* x_N    = (const float*)d_in[0];
    const float* We     = (const float*)d_in[1];
    const float* be     = (const float*)d_in[2];
    const float* Wg     = (const float*)d_in[3];
    const float* bg     = (const float*)d_in[4];
    const float* eps_g  = (const float*)d_in[5];
    const float* gam    = (const float*)d_in[6];
    const float* bet    = (const float*)d_in[7];
    const float* Wp     = (const float*)d_in[8];
    const float* bp     = (const float*)d_in[9];
    const int* ori_node = (const int*)d_in[10];
    const int* node2edge= (const int*)d_in[11];
    const int* eiN      = (const int*)d_in[12];
    const int* ori_edge = (const int*)d_in[13];
    const int* edge2node= (const int*)d_in[14];
    const int* eiE      = (const int*)d_in[15];
    const int* batch    = (const int*)d_in[16];

    const int NBLK = M_COPIES / 64;            // 6250 conv blocks / CSR regions

    char* p = (char*)d_ws;
    auto take = [&](size_t n) { char* r = p; p += (n + 255) & ~(size_t)255; return r; };
    unsigned short* Wt  = (unsigned short*)take((size_t)17 * 16384 * 2);
    unsigned short* Xb  = (unsigned short*)take((size_t)M_COPIES * 128 * 2);
    unsigned short* Xb2 = (unsigned short*)take((size_t)M_COPIES * 128 * 2);
    unsigned short* nx  = (unsigned short*)take((size_t)N_NODES * 128 * 2);
    unsigned short* ex  = (unsigned short*)take((size_t)N_EDGES * 128 * 2);
    float* y            = (float*)take((size_t)N_NODES * NCLS * 4);
    float* score        = (float*)take((size_t)NBATCH * NCLS * 4);
    // blkN/blkE in ONE allocation: NBLK*4 is not 256-aligned, and the memset
    // below must cover both arrays exactly (R4 crash lesson).
    int* blkN           = (int*)take((size_t)2 * NBLK * 4);
    int* blkE           = blkN + NBLK;
    int* off_n2e        = (int*)take((size_t)N_EDGES * 4);    // n2e/e2n contiguous
    int* off_e2n        = (int*)take((size_t)N_NODES * 4);
    int2* pkN           = (int2*)take((size_t)L_EDGES * 8);
    int2* pkE           = (int2*)take((size_t)L_EDGES * 8);
    int* it_n2e         = (int*)take((size_t)M_COPIES * 4);
    int* it_e2n         = (int*)take((size_t)M_COPIES * 4);
    int* part           = (int*)take((size_t)8192 * 4);
    size_t need = (size_t)(p - (char*)d_ws);
    if (need > ws_size) {
        fill_sentinel<<<(out_size + 63) / 64, 64, 0, stream>>>(
            (float*)d_out, out_size, 1.0e9f + (float)ws_size);
        return;
    }

    prep_w<<<1088, 256, 0, stream>>>(We, Wg, Wt);
    (void)hipMemsetAsync(score, 0, (size_t)NBATCH * NCLS * 4, stream);

    // ---- CSR builds ----
    const int NB_M = (M_COPIES + 255) / 256;   // 1563
    const int NB_L = (L_EDGES + 255) / 256;    // 3125
    const int NB_N = (N_NODES + 255) / 256;    // 196
    const int NB_B = (NBLK + 255) / 256;       // 25
    int* partB = part + 4096;

    // edge CSRs at block (64-row) granularity
    (void)hipMemsetAsync(blkN, 0, (size_t)2 * NBLK * 4, stream);   // one contiguous span
    hist2_k<<<NB_L, 256, 0, stream>>>(eiN + L_EDGES, L_EDGES, blkN,
                                      eiE + L_EDGES, L_EDGES, blkE, 6);
    scan1d_k<<<dim3(NB_B, 2), 256, 0, stream>>>(blkN, NBLK, part, blkE, NBLK, partB);
    scan2d_k<<<2, 256, 0, stream>>>(part, NB_B, partB, NB_B);
    scan3d_k<<<dim3(NB_B, 2), 256, 0, stream>>>(blkN, NBLK, part, blkE, NBLK, partB);
    fill_edgeblk2_k<<<NB_L, 256, 0, stream>>>(
        eiN, eiN + L_EDGES, ori_node, L_EDGES, blkN, pkN,
        eiE, eiE + L_EDGES, ori_edge, L_EDGES, blkE, pkE);

    // pool CSRs (off_n2e over N_EDGES segs, off_e2n over N_NODES segs)
    (void)hipMemsetAsync(off_n2e, 0,
        (size_t)((char*)off_e2n - (char*)off_n2e) + (size_t)N_NODES * 4, stream);
    hist2_k<<<NB_M, 256, 0, stream>>>(node2edge, M_COPIES, off_n2e,
                                      edge2node, M_COPIES, off_e2n, 0);
    scan1d_k<<<dim3(NB_N, 2), 256, 0, stream>>>(off_n2e, N_EDGES, part, off_e2n, N_NODES, partB);
    scan2d_k<<<2, 256, 0, stream>>>(part, (N_EDGES + 255) / 256, partB, NB_N);
    scan3d_k<<<dim3(NB_N, 2), 256, 0, stream>>>(off_n2e, N_EDGES, part, off_e2n, N_NODES, partB);
    fill_pool2_k<<<NB_M, 256, 0, stream>>>(node2edge, M_COPIES, off_n2e, it_n2e,
                                           edge2node, M_COPIES, off_e2n, it_e2n);

    gemm_embed<<<(N_NODES + 63) / 64, 256, 0, stream>>>(x_N, Wt, be, nx, N_NODES);
    proj_y<false><<<(N_NODES + 255) / 256, 256, 0, stream>>>(nx, Wp, y, N_NODES);

    for (int layer = 0; layer < 2; ++layer) {
        for (int dir = 0; dir < 2; ++dir) {
            int cj0 = layer * 4 + dir * 2;
            int cj1 = cj0 + 1;
            const unsigned short* base = (dir == 0) ? nx : ex;
            const int* selfI = (dir == 0) ? ori_node : ori_edge;
            const int* blkD  = (dir == 0) ? blkN : blkE;
            const int2* pkD  = (dir == 0) ? pkN : pkE;

            fused_conv<true><<<NBLK, 256, 0, stream>>>(
                base, selfI, blkD, pkD, eps_g + cj0,
                Wt + (size_t)(1 + cj0 * 2) * 16384, bg + (cj0 * 2) * 128,
                Wt + (size_t)(1 + cj0 * 2 + 1) * 16384, bg + (cj0 * 2 + 1) * 128,
                gam + cj0 * 128, bet + cj0 * 128, Xb);
            fused_conv<false><<<NBLK, 256, 0, stream>>>(
                Xb, nullptr, blkD, pkD, eps_g + cj1,
                Wt + (size_t)(1 + cj1 * 2) * 16384, bg + (cj1 * 2) * 128,
                Wt + (size_t)(1 + cj1 * 2 + 1) * 16384, bg + (cj1 * 2 + 1) * 128,
                gam + cj1 * 128, bet + cj1 * 128, Xb2);
            if (dir == 0) {
                segsum_pool<<<(N_EDGES + 3) / 4, 256, 0, stream>>>(
                    Xb2, off_n2e, it_n2e, ex, N_EDGES);
            } else {
                segsum_pool<<<(N_NODES + 3) / 4, 256, 0, stream>>>(
                    Xb2, off_e2n, it_e2n, nx, N_NODES);
                proj_y<true><<<(N_NODES + 255) / 256, 256, 0, stream>>>(
                    nx, Wp + (layer + 1) * HID * NCLS, y, N_NODES);
            }
        }
    }
    score_scatter<<<256, 256, 0, stream>>>(y, ori_node, batch, score);
    score_final<<<1, 320, 0, stream>>>(score, bp, (float*)d_out);
}